// Round 9
// baseline (1007.178 us; speedup 1.0000x reference)
//
#include <hip/hip_runtime.h>

#define DD 1024
#define LL 8
#define NN 8192
#define BB 32

typedef float vf4 __attribute__((ext_vector_type(4)));
typedef int   vi4 __attribute__((ext_vector_type(4)));

// ---------------------------------------------------------------------------
// Masked GEMM core (4 chunks of 32 q):
//   Tout[p][b] += sum_q act(in[q,b]) * W[p*ldw + q - qoff] * adj[q*NN + maskcol0 + p]
// TRANS=true : in = h, row-major [32][NN], staged with LDS transpose, act=identity
// TRANS=false: in = T, [q][b] layout, act=sigmoid
// Block: 128 threads (2 waves). Tile: 128 p x 32 b x 128 q. Reg tile 4p x 8b.
// Partials atomicAdd'ed into Tout (cross-block q reduction).
// ---------------------------------------------------------------------------
template <bool TRANS>
__device__ __forceinline__ void mg_core(
    const float* __restrict__ in,
    const float* __restrict__ W, int ldw, int qoff,
    const int* __restrict__ adj, int maskcol0,
    float* __restrict__ Tout, int p0, int q0)
{
  __shared__ float Wt[32][128];   // [q_local][p_local], transposed, 16 KB
  __shared__ int   aL[32][128];   // [q_local][p_local], straight,   16 KB
  __shared__ float ht[32][36];    // [q_local][b], padded rows (16B-aligned), 4.5 KB

  const int t  = threadIdx.x;     // 0..127
  const int pg = t & 31;          // p group: p_local = pg*4 .. pg*4+3
  const int bg = t >> 5;          // b group: b = bg*8 .. bg*8+7

  float acc[4][8];
#pragma unroll
  for (int pi = 0; pi < 4; ++pi)
#pragma unroll
    for (int bi = 0; bi < 8; ++bi) acc[pi][bi] = 0.f;

  const float* wrow = W + (size_t)(p0 + t) * ldw - qoff;  // staging row: p = p0 + t
  const size_t acol = (size_t)(maskcol0 + p0);

  for (int c = 0; c < 4; ++c) {
    const int q0c = q0 + c * 32;
    __syncthreads();  // previous chunk's compute done before overwriting LDS

    // --- batched global loads (nontemporal: W/adj are stream-once) ---
    vf4 wv[8];
    {
      const vf4* ws4 = (const vf4*)(wrow + q0c);
#pragma unroll
      for (int j = 0; j < 8; ++j) wv[j] = __builtin_nontemporal_load(ws4 + j);
    }
    vi4 av[8];
#pragma unroll
    for (int j = 0; j < 8; ++j) {                    // 32x128 int tile, linear 16B chunks
      int chunk = j * 128 + t;
      int n = chunk >> 5, cc = (chunk & 31) << 2;
      av[j] = __builtin_nontemporal_load(
          (const vi4*)(adj + (size_t)(q0c + n) * NN + acol + cc));
    }
    vf4 hv[2];
    if (TRANS) {
#pragma unroll
      for (int j = 0; j < 2; ++j)                    // h[b][q]: 32 rows x 32 q, coalesced
        hv[j] = *(const vf4*)(in + (size_t)((t >> 3) + 16 * j) * NN + q0c + (t & 7) * 4);
    } else {
#pragma unroll
      for (int j = 0; j < 2; ++j) {                  // T[q][b]: 32x32, linear
        int chunk = j * 128 + t;
        int n = chunk >> 3, bb = (chunk & 7) << 2;
        hv[j] = *(const vf4*)(in + (size_t)(q0c + n) * BB + bb);
        hv[j][0] = 1.f / (1.f + __expf(-hv[j][0]));  // sigmoid(activation) on read
        hv[j][1] = 1.f / (1.f + __expf(-hv[j][1]));
        hv[j][2] = 1.f / (1.f + __expf(-hv[j][2]));
        hv[j][3] = 1.f / (1.f + __expf(-hv[j][3]));
      }
    }

    // --- LDS writes ---
#pragma unroll
    for (int j = 0; j < 8; ++j) {                    // W transpose-write: banks t%32, 2-way = free
      Wt[j * 4 + 0][t] = wv[j][0];
      Wt[j * 4 + 1][t] = wv[j][1];
      Wt[j * 4 + 2][t] = wv[j][2];
      Wt[j * 4 + 3][t] = wv[j][3];
    }
#pragma unroll
    for (int j = 0; j < 8; ++j) ((vi4*)aL)[j * 128 + t] = av[j];
    if (TRANS) {
#pragma unroll
      for (int j = 0; j < 2; ++j) {                  // transpose: ht[q][b] = h[b][q]
        const int b = (t >> 3) + 16 * j, ql = (t & 7) * 4;
        ht[ql + 0][b] = hv[j][0];
        ht[ql + 1][b] = hv[j][1];
        ht[ql + 2][b] = hv[j][2];
        ht[ql + 3][b] = hv[j][3];
      }
    } else {
#pragma unroll
      for (int j = 0; j < 2; ++j) {
        int chunk = j * 128 + t;
        int n = chunk >> 3, bb = (chunk & 7) << 2;
        *(vf4*)&ht[n][bb] = hv[j];
      }
    }
    __syncthreads();

    // --- compute: 32 q-steps, 32 FMA each ---
#pragma unroll 4
    for (int j = 0; j < 32; ++j) {
      const vf4 w4 = *(const vf4*)&Wt[j][pg * 4];
      const vi4 a4 = *(const vi4*)&aL[j][pg * 4];
      float wm[4];
      wm[0] = w4[0] * (float)a4[0];
      wm[1] = w4[1] * (float)a4[1];
      wm[2] = w4[2] * (float)a4[2];
      wm[3] = w4[3] * (float)a4[3];
      const vf4 h0 = *(const vf4*)&ht[j][bg * 8];    // broadcast, free
      const vf4 h1 = *(const vf4*)&ht[j][bg * 8 + 4];
      const float h8[8] = {h0[0], h0[1], h0[2], h0[3], h1[0], h1[1], h1[2], h1[3]};
#pragma unroll
      for (int pi = 0; pi < 4; ++pi)
#pragma unroll
        for (int bi = 0; bi < 8; ++bi)
          acc[pi][bi] = fmaf(wm[pi], h8[bi], acc[pi][bi]);
    }
  }

#pragma unroll
  for (int pi = 0; pi < 4; ++pi)
#pragma unroll
    for (int bi = 0; bi < 8; ++bi)
      atomicAdd(&Tout[(p0 + pg * 4 + pi) * BB + bg * 8 + bi], acc[pi][bi]);
}

// ---------------------------------------------------------------------------
// Combined launch g: layer i = g-1 (if i>=0) + R-slab rk = g (if rk<=6).
// Always 448 blocks of 128 threads; block B: pt = B&7 (p-tile), cz = B>>3 (q-chunk).
//   cz < (i+1)*8           -> layer work:  q0 = cz*128, dst slab i+1
//   else                   -> R work:      q0 = (rk+1)*DD + (cz - lc)*128, dst slab rk
// Layer i: q<i*DD -> W_s[i-1] (ldw 6144), else W_h[i] (ldw 1024, qoff i*DD);
//          mask col base (i+1)*DD; input = sigmoid(T).
// R slab k: W_r[k] (ldw NN), mask col base k*DD; input = h (transposed stage).
// ---------------------------------------------------------------------------
__global__ __launch_bounds__(128) void k_mg(
    const float* __restrict__ T, const float* __restrict__ h,
    const float* __restrict__ W_h, const float* __restrict__ W_s,
    const float* __restrict__ W_r, const int* __restrict__ adj,
    float* __restrict__ Tmut, int i, int rk)
{
  const int B = blockIdx.x;
  const int pt = B & 7, cz = B >> 3;
  const int lc = (i >= 0) ? (i + 1) * 8 : 0;
  if (cz < lc) {
    const int q0 = cz * 128;
    const float* W; int ldw, qoff;
    if (q0 < i * DD) { W = W_s + (size_t)(i - 1) * DD * ((LL - 2) * DD); ldw = (LL - 2) * DD; qoff = 0; }
    else             { W = W_h + (size_t)i * DD * DD;                    ldw = DD;            qoff = i * DD; }
    mg_core<false>(T, W, ldw, qoff, adj, (i + 1) * DD,
                   Tmut + (size_t)(i + 1) * DD * BB, pt * 128, q0);
  } else {
    const int q0 = (rk + 1) * DD + (cz - lc) * 128;
    mg_core<true>(h, W_r + (size_t)rk * DD * NN, NN, 0, adj, rk * DD,
                  Tmut + (size_t)rk * DD * BB, pt * 128, q0);
  }
}

// Fused prep: slab 0 = b_in + x@W_in.T (dot over 256); slabs 1..7 = b_h broadcast.
// grid 1024 x 256: idx < 32768 -> xwin; else init.
__global__ void k_prep(const float* __restrict__ x, const float* __restrict__ W_in,
                       const float* __restrict__ b_in, const float* __restrict__ b_h,
                       float* __restrict__ T)
{
  int idx = blockIdx.x * 256 + threadIdx.x;      // 0..262143
  if (idx < DD * BB) {
    int p = idx >> 5, b = idx & 31;
    const vf4* xr = (const vf4*)(x + b * 256);
    const vf4* wr = (const vf4*)(W_in + p * 256);
    float acc = 0.f;
#pragma unroll 8
    for (int c = 0; c < 64; ++c) {
      vf4 xv = xr[c], wv = wr[c];
      acc += xv[0] * wv[0] + xv[1] * wv[1] + xv[2] * wv[2] + xv[3] * wv[3];
    }
    T[idx] = b_in[p] + acc;
  } else {
    int e = idx - DD * BB;                        // 0..229375
    T[DD * BB + e] = b_h[((e >> 15) << 10) + ((e >> 5) & (DD - 1))];
  }
}

// out[b][o] = b_o[o] + sum_p sigmoid(T7[p][b]) * W_o[o][p]; one block per b.
__global__ void k_out2(const float* __restrict__ T7, const float* __restrict__ W_o,
                       const float* __restrict__ b_o, float* __restrict__ out)
{
  __shared__ float sg[DD];
  const int b = blockIdx.x;        // 32 blocks
  const int t = threadIdx.x;       // 256 threads
#pragma unroll
  for (int j = 0; j < 4; ++j) {
    int p = j * 256 + t;
    float v = T7[p * BB + b];
    sg[p] = 1.f / (1.f + __expf(-v));
  }
  __syncthreads();
  const int o = t >> 2, quarter = t & 3;
  const vf4* wr = (const vf4*)(W_o + o * DD + quarter * 256);
  const vf4* sr = (const vf4*)(sg + quarter * 256);
  float acc = 0.f;
#pragma unroll 8
  for (int c = 0; c < 64; ++c) {
    vf4 wv = wr[c], sv = sr[c];
    acc += wv[0] * sv[0] + wv[1] * sv[1] + wv[2] * sv[2] + wv[3] * sv[3];
  }
  acc += __shfl_xor(acc, 1);
  acc += __shfl_xor(acc, 2);
  if (quarter == 0) out[b * 64 + o] = b_o[o] + acc;
}

extern "C" void kernel_launch(void* const* d_in, const int* in_sizes, int n_in,
                              void* d_out, int out_size, void* d_ws, size_t ws_size,
                              hipStream_t stream)
{
  const float* x    = (const float*)d_in[0];
  const float* h    = (const float*)d_in[1];
  const int*   adj  = (const int*)d_in[2];
  const float* W_in = (const float*)d_in[3];
  const float* b_in = (const float*)d_in[4];
  const float* W_h  = (const float*)d_in[5];
  const float* b_h  = (const float*)d_in[6];
  const float* W_r  = (const float*)d_in[7];
  const float* W_s  = (const float*)d_in[8];
  const float* W_o  = (const float*)d_in[9];
  const float* b_o  = (const float*)d_in[10];
  float* out = (float*)d_out;

  float* T = (float*)d_ws;            // [8][1024][32] pre-activations (1 MiB)

  k_prep<<<1024, 256, 0, stream>>>(x, W_in, b_in, b_h, T);
  // 8 uniform combined launches: 448 blocks / 56 MiB each.
  //   g=0: R slab 0 | g=1..6: layer g-1 + R slab g | g=7: layer 6
  for (int g = 0; g < 8; ++g) {
    int i  = g - 1;                   // layer index (-1: none)
    int rk = (g <= 6) ? g : -1;       // R slab (-1: none)
    k_mg<<<448, 128, 0, stream>>>(T, h, W_h, W_s, W_r, adj, T, i, rk);
  }
  k_out2<<<32, 256, 0, stream>>>(T + (size_t)7 * DD * BB, W_o, b_o, out);
}

// Round 10
// 736.654 us; speedup vs baseline: 1.3672x; 1.3672x over previous
//
#include <hip/hip_runtime.h>

#define DD 1024
#define LL 8
#define NN 8192
#define BB 32

typedef float vf4 __attribute__((ext_vector_type(4)));
typedef int   vi4 __attribute__((ext_vector_type(4)));

// ws layout (float offsets):
//   X0 [1024][32]        @ 0        (b_in + x@W_in.T)
//   S  [8192][32]        @ 32768    (final sigmoid activations, [q][b])
//   P  [8][56][1024][32] @ 294912   (per-chunk partial sums, no atomics)
#define WS_X0 0
#define WS_S  32768
#define WS_P  294912
#define PSLAB (56 * 32768)

// ---------------------------------------------------------------------------
// Masked GEMM partial core (4 chunks of 32 q):
//   Pout[p][b] = sum_{q in [q0,q0+128)} in(q,b) * W[p*ldw + q - qoff]
//                * (float)adj[q*NN + maskcol0 + p]
// TRANS=true : in = h row-major [32][NN], staged via LDS transpose
// TRANS=false: in = S [q][b] (already sigmoided)
// Block 128 thr. Tile 128p x 32b x 128q. Reg tile 4p x 8b. Plain stores.
// ---------------------------------------------------------------------------
template <bool TRANS>
__device__ __forceinline__ void mg_core(
    const float* __restrict__ in,
    const float* __restrict__ W, int ldw, int qoff,
    const int* __restrict__ adj, int maskcol0,
    float* __restrict__ Pout, int p0, int q0)
{
  __shared__ float Wt[32][132];   // [q_local][p_local], transposed, padded
  __shared__ int   aL[32][128];   // [q_local][p_local]
  __shared__ float ht[32][36];    // [q_local][b], padded

  const int t  = threadIdx.x;
  const int pg = t & 31;          // p_local = pg*4 .. pg*4+3
  const int bg = t >> 5;          // b = bg*8 .. bg*8+7

  float acc[4][8];
#pragma unroll
  for (int pi = 0; pi < 4; ++pi)
#pragma unroll
    for (int bi = 0; bi < 8; ++bi) acc[pi][bi] = 0.f;

  const float* wbase = W + (size_t)p0 * ldw - qoff;
  const size_t acol = (size_t)(maskcol0 + p0);

  for (int c = 0; c < 4; ++c) {
    const int q0c = q0 + c * 32;
    __syncthreads();

    // --- W: coalesced stage, 8 rows x 128B contiguous per instruction ---
    vf4 wv[8];
#pragma unroll
    for (int j = 0; j < 8; ++j) {
      int cid = j * 128 + t;                 // row = cid>>3, col4 = cid&7
      wv[j] = __builtin_nontemporal_load(
          (const vf4*)(wbase + (size_t)(cid >> 3) * ldw + q0c + (cid & 7) * 4));
    }
    // --- adj: 32 rows x 512B, coalesced ---
    vi4 av[8];
#pragma unroll
    for (int j = 0; j < 8; ++j) {
      int chunk = j * 128 + t;
      int n = chunk >> 5, cc = (chunk & 31) << 2;
      av[j] = __builtin_nontemporal_load(
          (const vi4*)(adj + (size_t)(q0c + n) * NN + acol + cc));
    }
    // --- activations ---
    vf4 hv[2];
    if (TRANS) {
#pragma unroll
      for (int j = 0; j < 2; ++j)            // h[b][q], coalesced
        hv[j] = *(const vf4*)(in + (size_t)((t >> 3) + 16 * j) * NN + q0c + (t & 7) * 4);
    } else {
#pragma unroll
      for (int j = 0; j < 2; ++j) {          // S[q][b], linear copy
        int chunk = j * 128 + t;
        hv[j] = *(const vf4*)(in + (size_t)(q0c + (chunk >> 3)) * BB + ((chunk & 7) << 2));
      }
    }

    // --- LDS writes ---
#pragma unroll
    for (int j = 0; j < 8; ++j) {            // W transpose-write (padded rows)
      int cid = j * 128 + t;
      int r = cid >> 3, c4 = (cid & 7) * 4;
      Wt[c4 + 0][r] = wv[j][0];
      Wt[c4 + 1][r] = wv[j][1];
      Wt[c4 + 2][r] = wv[j][2];
      Wt[c4 + 3][r] = wv[j][3];
    }
#pragma unroll
    for (int j = 0; j < 8; ++j) ((vi4*)aL)[j * 128 + t] = av[j];
    if (TRANS) {
#pragma unroll
      for (int j = 0; j < 2; ++j) {          // transpose: ht[q][b] = h[b][q]
        const int b = (t >> 3) + 16 * j, ql = (t & 7) * 4;
        ht[ql + 0][b] = hv[j][0];
        ht[ql + 1][b] = hv[j][1];
        ht[ql + 2][b] = hv[j][2];
        ht[ql + 3][b] = hv[j][3];
      }
    } else {
#pragma unroll
      for (int j = 0; j < 2; ++j) {
        int chunk = j * 128 + t;
        *(vf4*)&ht[chunk >> 3][(chunk & 7) << 2] = hv[j];
      }
    }
    __syncthreads();

    // --- compute: 32 q-steps, 32 FMA each ---
#pragma unroll 4
    for (int j = 0; j < 32; ++j) {
      const vf4 w4 = *(const vf4*)&Wt[j][pg * 4];
      const vi4 a4 = *(const vi4*)&aL[j][pg * 4];
      float wm[4];
      wm[0] = w4[0] * (float)a4[0];
      wm[1] = w4[1] * (float)a4[1];
      wm[2] = w4[2] * (float)a4[2];
      wm[3] = w4[3] * (float)a4[3];
      const vf4 h0 = *(const vf4*)&ht[j][bg * 8];
      const vf4 h1 = *(const vf4*)&ht[j][bg * 8 + 4];
      const float h8[8] = {h0[0], h0[1], h0[2], h0[3], h1[0], h1[1], h1[2], h1[3]};
#pragma unroll
      for (int pi = 0; pi < 4; ++pi)
#pragma unroll
        for (int bi = 0; bi < 8; ++bi)
          acc[pi][bi] = fmaf(wm[pi], h8[bi], acc[pi][bi]);
    }
  }

  // --- plain partial stores (no atomics) ---
#pragma unroll
  for (int pi = 0; pi < 4; ++pi) {
    vf4 v0 = {acc[pi][0], acc[pi][1], acc[pi][2], acc[pi][3]};
    vf4 v1 = {acc[pi][4], acc[pi][5], acc[pi][6], acc[pi][7]};
    float* dst = Pout + (size_t)(p0 + pg * 4 + pi) * BB + bg * 8;
    *(vf4*)dst = v0;
    *(vf4*)(dst + 4) = v1;
  }
}

// All 7 R-slabs in one wide launch: 1792 blocks = 8 pt x sum_k 8*(7-k).
// Slab k chunk z (0..8(7-k)-1): q0 = (k+1)*DD + z*128; partial slot 8k+z.
__global__ __launch_bounds__(128) void k_mgr(
    const float* __restrict__ h, const float* __restrict__ W_r,
    const int* __restrict__ adj, float* __restrict__ ws)
{
  int B = blockIdx.x;
  int pt = B & 7, z = B >> 3;
  int k = 0;
  while (z >= (7 - k) * 8) { z -= (7 - k) * 8; ++k; }
  float* Pout = ws + WS_P + (size_t)k * PSLAB + (size_t)(8 * k + z) * 32768;
  mg_core<true>(h, W_r + (size_t)k * DD * NN, NN, 0, adj, k * DD,
                Pout, pt * 128, (k + 1) * DD + z * 128);
}

// Layer i: 64*(i+1) blocks; chunk cz q0 = cz*128; dst slab i+1 slot cz.
__global__ __launch_bounds__(128) void k_mgl(
    const float* __restrict__ Ws_i, const float* __restrict__ Wh_i, int i,
    const int* __restrict__ adj, float* __restrict__ ws)
{
  int B = blockIdx.x;
  int pt = B & 7, cz = B >> 3;
  int q0 = cz * 128;
  const float* W; int ldw, qoff;
  if (q0 < i * DD) { W = Ws_i; ldw = (LL - 2) * DD; qoff = 0; }
  else             { W = Wh_i; ldw = DD;            qoff = i * DD; }
  float* Pout = ws + WS_P + (size_t)(i + 1) * PSLAB + (size_t)cz * 32768;
  mg_core<false>(ws + WS_S, W, ldw, qoff, adj, (i + 1) * DD, Pout, pt * 128, q0);
}

// Reduce slab g: S[g] = sigmoid(base + sum of 56 partial chunks).
__global__ void k_red(const float* __restrict__ b_h, float* __restrict__ ws, int g)
{
  int idx = blockIdx.x * 256 + threadIdx.x;   // 32768
  float base = (g == 0) ? ws[WS_X0 + idx] : b_h[(g - 1) * DD + (idx >> 5)];
  const float* P = ws + WS_P + (size_t)g * PSLAB + idx;
  float s = 0.f;
#pragma unroll 8
  for (int c = 0; c < 56; ++c) s += P[(size_t)c * 32768];
  float v = base + s;
  ws[WS_S + g * 32768 + idx] = 1.f / (1.f + __expf(-v));
}

// X0[p][b] = b_in[p] + x[b].W_in[p]  (dot over 256)
__global__ void k_prep(const float* __restrict__ x, const float* __restrict__ W_in,
                       const float* __restrict__ b_in, float* __restrict__ ws)
{
  int idx = blockIdx.x * 256 + threadIdx.x;   // 32768
  int p = idx >> 5, b = idx & 31;
  const vf4* xr = (const vf4*)(x + b * 256);
  const vf4* wr = (const vf4*)(W_in + p * 256);
  float acc = 0.f;
#pragma unroll 8
  for (int c = 0; c < 64; ++c) {
    vf4 xv = xr[c], wv = wr[c];
    acc += xv[0] * wv[0] + xv[1] * wv[1] + xv[2] * wv[2] + xv[3] * wv[3];
  }
  ws[WS_X0 + idx] = b_in[p] + acc;
}

// out[b][o] = b_o[o] + sum_p S[7D+p][b] * W_o[o][p]; one block per b.
__global__ void k_out(const float* __restrict__ ws, const float* __restrict__ W_o,
                      const float* __restrict__ b_o, float* __restrict__ out)
{
  __shared__ float sg[DD];
  const int b = blockIdx.x;        // 32
  const int t = threadIdx.x;       // 256
#pragma unroll
  for (int j = 0; j < 4; ++j) {
    int p = j * 256 + t;
    sg[p] = ws[WS_S + 7 * 32768 + p * BB + b];
  }
  __syncthreads();
  const int o = t >> 2, quarter = t & 3;
  const vf4* wr = (const vf4*)(W_o + o * DD + quarter * 256);
  const vf4* sr = (const vf4*)(sg + quarter * 256);
  float acc = 0.f;
#pragma unroll 8
  for (int c = 0; c < 64; ++c) {
    vf4 wv = wr[c], sv = sr[c];
    acc += wv[0] * sv[0] + wv[1] * sv[1] + wv[2] * sv[2] + wv[3] * sv[3];
  }
  acc += __shfl_xor(acc, 1);
  acc += __shfl_xor(acc, 2);
  if (quarter == 0) out[b * 64 + o] = b_o[o] + acc;
}

extern "C" void kernel_launch(void* const* d_in, const int* in_sizes, int n_in,
                              void* d_out, int out_size, void* d_ws, size_t ws_size,
                              hipStream_t stream)
{
  const float* x    = (const float*)d_in[0];
  const float* h    = (const float*)d_in[1];
  const int*   adj  = (const int*)d_in[2];
  const float* W_in = (const float*)d_in[3];
  const float* b_in = (const float*)d_in[4];
  const float* W_h  = (const float*)d_in[5];
  const float* b_h  = (const float*)d_in[6];
  const float* W_r  = (const float*)d_in[7];
  const float* W_s  = (const float*)d_in[8];
  const float* W_o  = (const float*)d_in[9];
  const float* b_o  = (const float*)d_in[10];
  float* out = (float*)d_out;
  float* ws  = (float*)d_ws;

  k_prep<<<128, 256, 0, stream>>>(x, W_in, b_in, ws);
  k_mgr<<<1792, 128, 0, stream>>>(h, W_r, adj, ws);   // all 7 R-slabs, wide
  k_red<<<128, 256, 0, stream>>>(b_h, ws, 0);
  for (int i = 0; i < 7; ++i) {
    k_mgl<<<64 * (i + 1), 128, 0, stream>>>(
        W_s + (size_t)(i > 0 ? i - 1 : 0) * DD * ((LL - 2) * DD),
        W_h + (size_t)i * DD * DD, i, adj, ws);
    k_red<<<128, 256, 0, stream>>>(b_h, ws, i + 1);
  }
  k_out<<<32, 256, 0, stream>>>(ws, W_o, b_o, out);
}